// Round 10
// baseline (193.374 us; speedup 1.0000x reference)
//
#include <hip/hip_runtime.h>
#include <cstddef>
#include <cstdint>

#define SEQ 2048
#define DM 1024
#define NH 16
#define HD 64

typedef _Float16 f16;
typedef __attribute__((ext_vector_type(8))) _Float16 f16x8;
typedef __attribute__((ext_vector_type(4))) _Float16 f16x4;
typedef __attribute__((ext_vector_type(2))) _Float16 f16x2;
typedef __attribute__((ext_vector_type(4))) float f32x4;

// one launch: cast x (1M float4) + 4 weights (256K float4 each) into the
// contiguous 16 MB f16 region [xb | Wq | Wk | Wv | Wo]
__global__ __launch_bounds__(256) void cast_all(const float* __restrict__ x,
                                                const float* __restrict__ Wq,
                                                const float* __restrict__ Wk,
                                                const float* __restrict__ Wv,
                                                const float* __restrict__ Wo,
                                                f16* __restrict__ dst) {
  const int i = blockIdx.x * 256 + threadIdx.x;  // float4 index, 2M total
  const float* src;
  int off;
  if (i < 1048576) {
    src = x; off = i;
  } else {
    const int j = i - 1048576;
    const int wsel = j >> 18;
    src = (wsel == 0) ? Wq : (wsel == 1) ? Wk : (wsel == 2) ? Wv : Wo;
    off = j & 262143;
  }
  const float4 v = ((const float4*)src)[off];
  f16x4 o = {(f16)v.x, (f16)v.y, (f16)v.z, (f16)v.w};
  ((f16x4*)dst)[i] = o;
}

__device__ __forceinline__ void gload16(const void* g, void* lds) {
  __builtin_amdgcn_global_load_lds((const __attribute__((address_space(1))) void*)g,
                                   (__attribute__((address_space(3))) void*)lds,
                                   16, 0, 0);
}

// ---------------------------------------------------------------------------
// f16 GEMM mainloop (m97 structure).
// ---------------------------------------------------------------------------
__device__ __forceinline__ void gemm_tile(const f16* __restrict__ A,
                                          const f16* __restrict__ B,
                                          f16* As, f16* Bs,
                                          int K, f32x4 acc[4][4]) {
  const int t = threadIdx.x;
  const int lane = t & 63;
  const int w = t >> 6;
  const int wm = (w & 1) << 6, wn = (w >> 1) << 6;
  const int srow = lane >> 2, scol = lane & 3;
  const int fr = lane & 15, q = lane >> 4;
  for (int k0 = 0; k0 < K; k0 += 32) {
    __syncthreads();
#pragma unroll
    for (int c = 0; c < 2; ++c) {
      const int chunk = (w << 1) + c;
      const int row = (chunk << 4) + srow;
      gload16(A + (size_t)row * K + k0 + (scol << 3), As + (chunk << 9));
      gload16(B + (size_t)row * K + k0 + (scol << 3), Bs + (chunk << 9));
    }
    __syncthreads();
    f16x8 af[4], bfr[4];
#pragma unroll
    for (int i = 0; i < 4; ++i)
      af[i] = *(const f16x8*)(As + (wm + (i << 4) + fr) * 32 + (q << 3));
#pragma unroll
    for (int j = 0; j < 4; ++j)
      bfr[j] = *(const f16x8*)(Bs + (wn + (j << 4) + fr) * 32 + (q << 3));
#pragma unroll
    for (int i = 0; i < 4; ++i)
#pragma unroll
      for (int j = 0; j < 4; ++j)
        acc[i][j] = __builtin_amdgcn_mfma_f32_16x16x32_f16(af[i], bfr[j],
                                                           acc[i][j], 0, 0, 0);
  }
}

// Fused QKV projection. Q pre-scaled by log2(e)/sqrt(d_model).
// R10: Q/K epilogue via LDS transpose (pad 132, 2-way max) -> coalesced
// f16x8 row-major stores. V epilogue: DIRECT frag-layout f16x4 stores
// (C-frag regs are 4 consecutive s; Vtg is s-inner -> 128B runs, no LDS).
//   Vtg flat(d,s) = bh*131072 + (s>>6)*4096 + ((s>>2)&15)*256 + d*4 + (s&3)
#define QSCALE 0.04508422003f /* 1.4426950409/32 */
__global__ __launch_bounds__(256) void gemm_qkv(
    const f16* __restrict__ xb, const f16* __restrict__ Wqb,
    const f16* __restrict__ Wkb, const f16* __restrict__ Wvb,
    f16* __restrict__ Qb, f16* __restrict__ Kb, f16* __restrict__ Vtg) {
  __shared__ f16 smem[16896];  // staging 16KB in [0:8192); epilogue T 33KB
  f16* As = smem;
  f16* Bs = smem + 4096;
  const int which = blockIdx.x >> 3;
  const int bn = (blockIdx.x & 7) << 7;
  const int bm = blockIdx.y << 7;
  const f16* B = (which == 0) ? Wqb : (which == 1) ? Wkb : Wvb;
  f32x4 acc[4][4] = {};
  gemm_tile(xb + (size_t)bm * DM, B + (size_t)bn * DM, As, Bs, DM, acc);
  const int t = threadIdx.x;
  const int lane = t & 63, w = t >> 6;
  const int wm = (w & 1) << 6, wn = (w >> 1) << 6;
  const int col = lane & 15, q = lane >> 4;
  if (which < 2) {
    f16* C = (which == 0) ? Qb : Kb;
    const float sc = (which == 0) ? QSCALE : 1.0f;
    __syncthreads();  // waves done with As/Bs MFMA reads; smem reused as T
#pragma unroll
    for (int i = 0; i < 4; ++i) {
      const int m0 = wm + (i << 4) + (q << 2);
#pragma unroll
      for (int j = 0; j < 4; ++j) {
        const int n = wn + (j << 4) + col;
#pragma unroll
        for (int r = 0; r < 4; ++r)
          smem[(m0 + r) * 132 + n] = (f16)(acc[i][j][r] * sc);
      }
    }
    __syncthreads();
#pragma unroll
    for (int p = 0; p < 8; ++p) {
      const int idx = t + (p << 8);          // 0..2047
      const int row = idx >> 4, c8 = (idx & 15) << 3;
      const f16x8 v = *(const f16x8*)(smem + row * 132 + c8);
      *(f16x8*)(C + (size_t)(bm + row) * DM + bn + c8) = v;
    }
  } else {
    // direct frag-layout stores: no LDS, no barriers
    const int b = bm >> 11, sb = bm & 2047;
#pragma unroll
    for (int i = 0; i < 4; ++i) {
      const int sg = sb + wm + (i << 4) + (q << 2);  // s (mult of 4)
#pragma unroll
      for (int j = 0; j < 4; ++j) {
        const int n = bn + wn + (j << 4) + col;
        const int bh = (b << 4) + (n >> 6), d = n & 63;
        f16x4 o = {(f16)acc[i][j][0], (f16)acc[i][j][1],
                   (f16)acc[i][j][2], (f16)acc[i][j][3]};
        const size_t flat = ((size_t)bh << 17) + ((size_t)(sg >> 6) << 12) +
                            (((sg >> 2) & 15) << 8) + (d << 2);
        *(f16x4*)(Vtg + flat) = o;
      }
    }
  }
}

__global__ __launch_bounds__(256) void gemm_out(const f16* __restrict__ Ab,
                                                const f16* __restrict__ Wob,
                                                float* __restrict__ out) {
  __shared__ f16 As[128 * 32];
  __shared__ f16 Bs[128 * 32];
  const int bn = blockIdx.x << 7, bm = blockIdx.y << 7;
  f32x4 acc[4][4] = {};
  gemm_tile(Ab + (size_t)bm * DM, Wob + (size_t)bn * DM, As, Bs, DM, acc);
  const int lane = threadIdx.x & 63, w = threadIdx.x >> 6;
  const int wm = (w & 1) << 6, wn = (w >> 1) << 6;
  const int col = lane & 15, q = lane >> 4;
#pragma unroll
  for (int i = 0; i < 4; ++i) {
    const int m = bm + wm + (i << 4) + (q << 2);
#pragma unroll
    for (int j = 0; j < 4; ++j) {
      const int n = bn + wn + (j << 4) + col;
#pragma unroll
      for (int r = 0; r < 4; ++r)
        out[(size_t)(m + r) * DM + n] = acc[i][j][r];
    }
  }
}

// ---------------------------------------------------------------------------
// MFMA flash attention (R9 structure, unchanged — at its K-loop plateau).
// ---------------------------------------------------------------------------
__global__ __launch_bounds__(256, 2) void attn_mfma(const f16* __restrict__ Qb,
                                                    const f16* __restrict__ Kb,
                                                    const f16* __restrict__ Vtg,
                                                    f16* __restrict__ Ctx) {
  __shared__ f16 smem[8192];  // 16 KB: K img0 [0:4096) | img1 [4096:8192)
  const int t = threadIdx.x, lane = t & 63, w = t >> 6;
  const int fr = lane & 15, quad = lane >> 4;
  const int i = blockIdx.x;
  const int j = i >> 3;
  const int bh = ((i & 7) << 2) + (j >> 4);
  const int qt16 = j & 15;
  const int b = bh >> 4, h = bh & 15;

  const size_t qrow0 = (size_t)b * SEQ + qt16 * 128 + w * 32;

  // Q^T B-frags, loop-invariant
  f16x8 Qf[2][2];
#pragma unroll
  for (int qt = 0; qt < 2; ++qt)
#pragma unroll
    for (int hf = 0; hf < 2; ++hf)
      Qf[qt][hf] = *(const f16x8*)(Qb + (qrow0 + qt * 16 + fr) * DM + h * HD +
                                   hf * 32 + (quad << 3));

  // K reg-staging: lane -> (row16 = lane>>2, kc = lane&3), wave w rows 16w..+15
  const int krow = lane >> 2, kkc = lane & 3;
  const f16* Kg = Kb + ((size_t)b * SEQ + 16 * w + krow) * DM + h * HD + (kkc << 3);
  const int cwr = ((krow >> 1) << 3) | ((krow & 1) << 2) | (((krow >> 1) + kkc) & 3);
  const int wofs = (w << 9) + (cwr << 3);
  const int crd = ((fr >> 1) << 3) | ((fr & 1) << 2) | (((fr >> 1) + quad) & 3);

  // V frag-layout source (bh stride 131072, tile stride 4096)
  const f16* Vg = Vtg + ((size_t)bh << 17) + (quad << 8) + (fr << 2);

  f16x8 kreg[2];
  f16x4 va[4][4], vb[4][4];
  auto loadK = [&](int kt) {
#pragma unroll
    for (int hf = 0; hf < 2; ++hf)
      kreg[hf] = *(const f16x8*)(Kg + (size_t)kt * 64 * DM + hf * 32);
  };
  auto loadV = [&](int kt, f16x4 (&vr)[4][4]) {
#pragma unroll
    for (int kc = 0; kc < 4; ++kc)
#pragma unroll
      for (int dt = 0; dt < 4; ++dt)
        vr[dt][kc] = *(const f16x4*)(Vg + kt * 4096 + (kc << 10) + (dt << 6));
  };

  f32x4 acc[2][4] = {};
  float lacc[2] = {0.f, 0.f};

  f16* img0 = smem;
  f16* img1 = smem + 4096;

  loadK(0);
  loadV(0, va);
  *(f16x8*)(img0 + wofs) = kreg[0];
  *(f16x8*)(img0 + wofs + 2048) = kreg[1];

  auto body = [&](int kt, f16x4 (&vcur)[4][4], f16x4 (&vnxt)[4][4],
                  f16* imgR, f16* imgW) {
    __syncthreads();  // publishes imgR (tile kt); drains loads issued last body
    if (kt < 31) {
      loadK(kt + 1);
      loadV(kt + 1, vnxt);
    }
    f16x8 Kf[4][2];
#pragma unroll
    for (int mt = 0; mt < 4; ++mt)
#pragma unroll
      for (int hf = 0; hf < 2; ++hf)
        Kf[mt][hf] = *(const f16x8*)(imgR + (crd << 3) + hf * 2048 + (mt << 9));

    f16x4 pf[2][4];
#pragma unroll
    for (int qt = 0; qt < 2; ++qt) {
      f32x4 z[4] = {};
#pragma unroll
      for (int mt = 0; mt < 4; ++mt) {
        z[mt] = __builtin_amdgcn_mfma_f32_16x16x32_f16(Kf[mt][0], Qf[qt][0],
                                                       z[mt], 0, 0, 0);
        z[mt] = __builtin_amdgcn_mfma_f32_16x16x32_f16(Kf[mt][1], Qf[qt][1],
                                                       z[mt], 0, 0, 0);
      }
#pragma unroll
      for (int mt = 0; mt < 4; ++mt) {
        const float p0 = __builtin_amdgcn_exp2f(z[mt][0]);
        const float p1 = __builtin_amdgcn_exp2f(z[mt][1]);
        const float p2 = __builtin_amdgcn_exp2f(z[mt][2]);
        const float p3 = __builtin_amdgcn_exp2f(z[mt][3]);
        lacc[qt] += (p0 + p1) + (p2 + p3);
        const f16x2 lo = __builtin_bit_cast(f16x2, __builtin_amdgcn_cvt_pkrtz(p0, p1));
        const f16x2 hi = __builtin_bit_cast(f16x2, __builtin_amdgcn_cvt_pkrtz(p2, p3));
        f16x4 pv; pv.x = lo.x; pv.y = lo.y; pv.z = hi.x; pv.w = hi.y;
        pf[qt][mt] = pv;
      }
    }

#pragma unroll
    for (int dt = 0; dt < 4; ++dt)
#pragma unroll
      for (int kc = 0; kc < 4; ++kc)
#pragma unroll
        for (int qt = 0; qt < 2; ++qt)
          acc[qt][dt] = __builtin_amdgcn_mfma_f32_16x16x16f16(vcur[dt][kc],
                                                              pf[qt][kc],
                                                              acc[qt][dt], 0, 0, 0);
    if (kt < 31) {
      *(f16x8*)(imgW + wofs) = kreg[0];
      *(f16x8*)(imgW + wofs + 2048) = kreg[1];
    }
  };

  for (int kt = 0; kt < 32; kt += 2) {
    body(kt, va, vb, img0, img1);
    body(kt + 1, vb, va, img1, img0);
  }

  // l reduction over quads (lanes fr, fr+16, fr+32, fr+48 share a q-col)
  float inv[2];
#pragma unroll
  for (int qt = 0; qt < 2; ++qt) {
    float l = lacc[qt];
    l += __shfl_xor(l, 16);
    l += __shfl_xor(l, 32);
    inv[qt] = __builtin_amdgcn_rcpf(l);
  }

  __syncthreads();  // done with K images before epilogue reuse
  f16* T = smem + (w << 11);  // wave-private [32 q][64 d]
#pragma unroll
  for (int qt = 0; qt < 2; ++qt)
#pragma unroll
    for (int dt = 0; dt < 4; ++dt) {
      f16x4 o = {(f16)(acc[qt][dt][0] * inv[qt]), (f16)(acc[qt][dt][1] * inv[qt]),
                 (f16)(acc[qt][dt][2] * inv[qt]), (f16)(acc[qt][dt][3] * inv[qt])};
      *(f16x4*)(T + (qt * 16 + fr) * 64 + dt * 16 + (quad << 2)) = o;
    }
#pragma unroll
  for (int p = 0; p < 4; ++p) {
    const int ql = p * 8 + (lane >> 3);
    const f16x8 v = *(const f16x8*)(T + ql * 64 + ((lane & 7) << 3));
    *(f16x8*)(Ctx + (qrow0 + ql) * DM + h * HD + ((lane & 7) << 3)) = v;
  }
}

extern "C" void kernel_launch(void* const* d_in, const int* in_sizes, int n_in,
                              void* d_out, int out_size, void* d_ws, size_t ws_size,
                              hipStream_t stream) {
  const float* x  = (const float*)d_in[0];
  const float* Wq = (const float*)d_in[1];
  const float* Wk = (const float*)d_in[2];
  const float* Wv = (const float*)d_in[3];
  const float* Wo = (const float*)d_in[4];

  char* ws = (char*)d_ws;
  f16* xb  = (f16*)(ws);                 // 8 MB; Wb contiguous after it
  f16* Wb  = (f16*)(ws + (8u << 20));    // 4 x 2 MB: Wq,Wk,Wv,Wo
  f16* Wqb = Wb;
  f16* Wkb = Wb + 1048576;
  f16* Wvb = Wb + 2097152;
  f16* Wob = Wb + 3145728;
  f16* Qb  = (f16*)(ws + (16u << 20));   // 8 MB (pre-scaled by log2e/32)
  f16* Kb  = (f16*)(ws + (24u << 20));
  f16* Vtg = (f16*)(ws + (32u << 20));   // frag-layout V, 8 MB
  f16* Ctx = (f16*)(ws + (40u << 20));   // -> 48 MB total

  cast_all<<<8192, 256, 0, stream>>>(x, Wq, Wk, Wv, Wo, xb);

  gemm_qkv<<<dim3(24, 32), 256, 0, stream>>>(xb, Wqb, Wkb, Wvb, Qb, Kb, Vtg);
  attn_mfma<<<dim3(2 * NH * (SEQ / 128)), 256, 0, stream>>>(Qb, Kb, Vtg, Ctx);
  gemm_out<<<dim3(8, 32), 256, 0, stream>>>(Ctx, Wob, (float*)d_out);
}